// Round 16
// baseline (580.073 us; speedup 1.0000x reference)
//
#include <hip/hip_runtime.h>
#include <cstdint>
#include <cstddef>

#define BATCH   4096
#define INDIM   1024
#define DICT    16384
#define TOTK    (32 * 4096)
#define NFEAT   ((size_t)BATCH * DICT)   // 67108864
#define DELTA   3e-2f                    // zone half-width; >= 2*maxerr(hi*hi GEMM)
#define BAND    0.2f                     // presample band margin
#define PS_RANK (TOTK / 32)              // rank in 128-row sample (1/32 of batch)

#define NB2       4096            // coarse bins (u >> 19)
#define FBINS     2048            // fine-hist bins over [BL,BH)
#define HCOPIES   64
#define CAND_CAP  (1u << 19)
#define BCAP      256u            // per-block candidate cap (avg ~52)
#define ZLOC_CAP  2048u           // per-block in-zone cap in findfine_b
#define CLOC_CAP  3072
#define C2_CAP    65536u
#define HASH_SZ   32768u
#define ROW_CAP   512
#define ZBINS     2048

// ---- ws layout ----
// [0,16K) pshist | [16K,24K) fhist | [32K,+256) scal |
// [36K,40K) h1(fb) | [40K,56K) rowcnt | [64K,320K) hash |
// [512K,1536K) fbhist 64x4096 | [2M,4M) candI | [4M,6M) candB |
// [6M,+256K) c2idx | [6M+256K,+256K) c2val | [7M,23M) entries |
// [24M,32M) Ahi | [32M,64M) Bhi | Wt(bf16,32M) overlays [24M,56M) after fb_encode
// scal: 0=fbBin,1=fbAbove,2=candCnt,3=fbThr,4=l0,6=ZL,7=ZH,8=aboveZone,
//       9=c2cnt,10=fbAboveB1,11=vj,12..13=loss(f64),16=aboveBH,17=ovf,
//       18=OK,20=BLbits,21=BHbits,24=fbCandCnt
#define PSH_OFF   0ull
#define FH_OFF    16384ull
#define SCAL_OFF  32768ull
#define H1_OFF    36864ull
#define ROWC_OFF  40960ull
#define HASH_OFF  65536ull
#define FBH_OFF   524288ull
#define MEMSET0   1572864ull
#define CANDI_OFF (2ull << 20)
#define CANDB_OFF (4ull << 20)
#define C2I_OFF   (6ull << 20)
#define C2V_OFF   ((6ull << 20) + 262144)
#define ENT_OFF   (7ull << 20)
#define AHI_OFF   (24ull << 20)
#define BHI_OFF   (32ull << 20)
#define WT_OFF    (24ull << 20)
#define WS_NEED   (88ull << 20)

typedef __attribute__((ext_vector_type(8))) short short8;
typedef __attribute__((ext_vector_type(4))) float f32x4;

#define GL2LDS16(g, l) __builtin_amdgcn_global_load_lds( \
    (const __attribute__((address_space(1))) void*)(g), \
    (__attribute__((address_space(3))) void*)(l), 16, 0, 0)

__device__ inline ushort bf16_rne_u(float a) {
    unsigned u = __float_as_uint(a);
    return (ushort)((u + 0x7FFFu + ((u >> 16) & 1u)) >> 16);
}

__device__ inline float bf16_to_f(ushort u) {
    return __uint_as_float(((unsigned)u) << 16);
}

__device__ inline int fshift_calc(unsigned BL, unsigned BH) {
    const unsigned range = BH - BL;
    int s = 0;
    while ((range >> s) > (unsigned)FBINS) ++s;
    return s;
}

// ======== split: Ahi = bf16(x - b_dec), Bhi = bf16(W_enc) ========
__global__ __launch_bounds__(256) void split_kernel(
    const float* __restrict__ x, const float* __restrict__ W,
    const float* __restrict__ b_dec,
    ushort* __restrict__ Ahi, ushort* __restrict__ Bhi)
{
    const size_t NA = (size_t)BATCH * INDIM / 4;
    const size_t NB = (size_t)DICT * INDIM / 4;
    const size_t stride = (size_t)gridDim.x * blockDim.x;
    for (size_t i = (size_t)blockIdx.x * blockDim.x + threadIdx.x; i < NA + NB; i += stride) {
        float4 v;
        ushort* hp;
        if (i < NA) {
            v = reinterpret_cast<const float4*>(x)[i];
            const float4 bd = reinterpret_cast<const float4*>(b_dec)[i & (INDIM / 4 - 1)];
            v.x -= bd.x; v.y -= bd.y; v.z -= bd.z; v.w -= bd.w;
            hp = Ahi + i * 4;
        } else {
            v = reinterpret_cast<const float4*>(W)[i - NA];
            hp = Bhi + (i - NA) * 4;
        }
        ushort4 h;
        h.x = bf16_rne_u(v.x);
        h.y = bf16_rne_u(v.y);
        h.z = bf16_rne_u(v.z);
        h.w = bf16_rne_u(v.w);
        *reinterpret_cast<ushort4*>(hp) = h;
    }
}

// ======== presample: rows 0..127, all cols; coarse hist only ========
__global__ __launch_bounds__(256) void presample_mfma(
    const ushort* __restrict__ Ahi, const ushort* __restrict__ Bhi,
    const float* __restrict__ b_enc, unsigned* __restrict__ pshist)
{
    __shared__ __align__(16) ushort As[128 * 64];
    __shared__ __align__(16) ushort Bs[128 * 64];
    __shared__ unsigned hls[NB2];
    const int tid = threadIdx.x;
    const int lane = tid & 63, wid = tid >> 6;
    const int n0 = blockIdx.x * 128;
    const int m0 = 0;
    const int wm = wid >> 1, wn = wid & 1;

    for (int i = tid; i < NB2; i += 256) hls[i] = 0;

    f32x4 acc[4][4];
#pragma unroll
    for (int i = 0; i < 4; ++i)
#pragma unroll
        for (int j = 0; j < 4; ++j) acc[i][j] = (f32x4){0.f, 0.f, 0.f, 0.f};

    const int srow = wid * 8 + (lane >> 3);
    const int schunk = (lane & 7) ^ (lane >> 3);
    const size_t abase = (size_t)(m0 + srow) * INDIM + schunk * 8;
    const size_t bbase = (size_t)(n0 + srow) * INDIM + schunk * 8;

    for (int t = 0; t < 16; ++t) {
        const int koff = t * 64;
#pragma unroll
        for (int i = 0; i < 4; ++i) {
            GL2LDS16(Ahi + abase + koff + (size_t)i * 32 * INDIM, &As[(i * 32 + wid * 8) * 64]);
            GL2LDS16(Bhi + bbase + koff + (size_t)i * 32 * INDIM, &Bs[(i * 32 + wid * 8) * 64]);
        }
        __syncthreads();
#pragma unroll
        for (int kq2 = 0; kq2 < 2; ++kq2) {
            short8 af[4], bf[4];
#pragma unroll
            for (int f = 0; f < 4; ++f) {
                const int ra = wm * 64 + f * 16 + (lane & 15);
                const int ca = (kq2 * 4 + (lane >> 4)) ^ (ra & 7);
                af[f] = *reinterpret_cast<const short8*>(&As[ra * 64 + ca * 8]);
                const int rb = wn * 64 + f * 16 + (lane & 15);
                const int cb = (kq2 * 4 + (lane >> 4)) ^ (rb & 7);
                bf[f] = *reinterpret_cast<const short8*>(&Bs[rb * 64 + cb * 8]);
            }
#pragma unroll
            for (int fm = 0; fm < 4; ++fm)
#pragma unroll
                for (int fn = 0; fn < 4; ++fn)
                    acc[fm][fn] = __builtin_amdgcn_mfma_f32_16x16x32_bf16(
                        af[fm], bf[fn], acc[fm][fn], 0, 0, 0);
        }
        __syncthreads();
    }

    const int ccol0 = n0 + wn * 64;
#pragma unroll
    for (int fm = 0; fm < 4; ++fm) {
#pragma unroll
        for (int fn = 0; fn < 4; ++fn) {
            const int col = ccol0 + fn * 16 + (lane & 15);
            const float be = b_enc[col];
#pragma unroll
            for (int r = 0; r < 4; ++r) {
                const float val = fmaxf(acc[fm][fn][r] + be, 0.f);
                if (val > 0.f) atomicAdd(&hls[__float_as_uint(val) >> 19], 1u);
            }
        }
    }
    __syncthreads();
    for (int i = tid; i < NB2; i += 256)
        if (hls[i]) atomicAdd(&pshist[i], hls[i]);
}

// ======== presample_find: coarse bin of sample rank -> band [BL,BH] ========
__global__ __launch_bounds__(1024) void presample_find(const unsigned* __restrict__ pshist,
                                                       unsigned* __restrict__ scal)
{
    __shared__ unsigned tot[NB2];
    __shared__ unsigned tsum[1024];
    __shared__ unsigned suffix[1024];
    const int t = threadIdx.x;
    unsigned s = 0;
#pragma unroll
    for (int i = 0; i < 4; ++i) {
        const int b = t * 4 + i;
        const unsigned v = pshist[b];
        tot[b] = v;
        s += v;
    }
    tsum[t] = s;
    __syncthreads();
    if (t == 0) {
        unsigned run = 0;
        for (int i = 1023; i >= 0; --i) { suffix[i] = run; run += tsum[i]; }
    }
    __syncthreads();
    unsigned cum = suffix[t];
    for (int i = 3; i >= 0; --i) {
        const unsigned b = (unsigned)(t * 4 + i);
        const unsigned nb = cum + tot[b];
        if (cum < PS_RANK && nb >= PS_RANK) {
            const float blo = __uint_as_float(b << 19);
            const float bhi = __uint_as_float((b + 1) << 19);
            scal[20] = __float_as_uint(fmaxf(blo - BAND, 1e-30f));
            scal[21] = __float_as_uint(bhi + BAND);
        }
        cum = nb;
    }
}

// ======== encode_main: MFMA + candidate emit + fine hist + vector zero-fill ========
__global__ __launch_bounds__(256) void encode_main(
    const ushort* __restrict__ Ahi, const ushort* __restrict__ Bhi,
    const float* __restrict__ b_enc, unsigned* __restrict__ scal,
    unsigned* __restrict__ fhist, unsigned* __restrict__ candI,
    unsigned* __restrict__ candB, float* __restrict__ feat)
{
    __shared__ __align__(16) ushort As[128 * 64];
    __shared__ __align__(16) ushort Bs[128 * 64];
    __shared__ unsigned ci[BCAP];
    __shared__ unsigned cb[BCAP];
    __shared__ unsigned lcnt, labv, sbase;
    const int tid = threadIdx.x;
    const int lane = tid & 63, wid = tid >> 6;
    // XCD slab ordering: 16 n-tiles per XCD (4MB B in L2), m cycles slowest
    const int flat = blockIdx.y * gridDim.x + blockIdx.x;
    const int n0 = ((flat & 7) * 16 + ((flat >> 3) & 15)) * 128;
    const int m0 = (flat >> 7) * 128;
    const int wm = wid >> 1, wn = wid & 1;

    if (tid == 0) { lcnt = 0; labv = 0; }

    const unsigned BLb = scal[20], BHb = scal[21];
    const float BLf = __uint_as_float(BLb);
    const int fs = fshift_calc(BLb, BHb);

    f32x4 acc[4][4];
#pragma unroll
    for (int i = 0; i < 4; ++i)
#pragma unroll
        for (int j = 0; j < 4; ++j) acc[i][j] = (f32x4){0.f, 0.f, 0.f, 0.f};

    const int srow = wid * 8 + (lane >> 3);
    const int schunk = (lane & 7) ^ (lane >> 3);
    const size_t abase = (size_t)(m0 + srow) * INDIM + schunk * 8;
    const size_t bbase = (size_t)(n0 + srow) * INDIM + schunk * 8;

    for (int t = 0; t < 16; ++t) {
        const int koff = t * 64;
#pragma unroll
        for (int i = 0; i < 4; ++i) {
            GL2LDS16(Ahi + abase + koff + (size_t)i * 32 * INDIM, &As[(i * 32 + wid * 8) * 64]);
            GL2LDS16(Bhi + bbase + koff + (size_t)i * 32 * INDIM, &Bs[(i * 32 + wid * 8) * 64]);
        }
        __syncthreads();
#pragma unroll
        for (int kq2 = 0; kq2 < 2; ++kq2) {
            short8 af[4], bf[4];
#pragma unroll
            for (int f = 0; f < 4; ++f) {
                const int ra = wm * 64 + f * 16 + (lane & 15);
                const int ca = (kq2 * 4 + (lane >> 4)) ^ (ra & 7);
                af[f] = *reinterpret_cast<const short8*>(&As[ra * 64 + ca * 8]);
                const int rb = wn * 64 + f * 16 + (lane & 15);
                const int cbx = (kq2 * 4 + (lane >> 4)) ^ (rb & 7);
                bf[f] = *reinterpret_cast<const short8*>(&Bs[rb * 64 + cbx * 8]);
            }
#pragma unroll
            for (int fm = 0; fm < 4; ++fm)
#pragma unroll
                for (int fn = 0; fn < 4; ++fn)
                    acc[fm][fn] = __builtin_amdgcn_mfma_f32_16x16x32_bf16(
                        af[fm], bf[fn], acc[fm][fn], 0, 0, 0);
        }
        __syncthreads();
    }

    // ---- plain vectorized zero-fill of this block's 128x128 tile ----
    {
        const f32x4 z = (f32x4){0.f, 0.f, 0.f, 0.f};
        f32x4* trow = reinterpret_cast<f32x4*>(feat + (size_t)(m0 + (tid >> 5)) * DICT + n0);
#pragma unroll
        for (int s = 0; s < 16; ++s) {
            trow[(tid & 31)] = z;
            trow += (size_t)8 * DICT / 4;   // advance 8 rows
        }
    }

    // ---- candidate detection from registers (no feat value writes) ----
    const int crow0 = m0 + wm * 64;
    const int ccol0 = n0 + wn * 64;
#pragma unroll
    for (int fm = 0; fm < 4; ++fm) {
#pragma unroll
        for (int fn = 0; fn < 4; ++fn) {
            const int col = ccol0 + fn * 16 + (lane & 15);
            const float be = b_enc[col];
#pragma unroll
            for (int r = 0; r < 4; ++r) {
                const int row = crow0 + fm * 16 + (lane >> 4) * 4 + r;
                const float val = fmaxf(acc[fm][fn][r] + be, 0.f);
                if (val >= BLf) {
                    const unsigned u = __float_as_uint(val);
                    if (u < BHb) atomicAdd(&fhist[min((u - BLb) >> fs, (unsigned)(FBINS - 1))], 1u);
                    else atomicAdd(&labv, 1u);
                    const unsigned p = atomicAdd(&lcnt, 1u);
                    if (p < BCAP) {
                        ci[p] = (unsigned)(row * DICT + col);
                        cb[p] = u;
                    }
                }
            }
        }
    }
    __syncthreads();
    if (tid == 0) {
        if (labv) atomicAdd(&scal[16], labv);
        const unsigned n = min(lcnt, BCAP);
        if (lcnt > BCAP) atomicExch(&scal[17], 1u);
        sbase = atomicAdd(&scal[2], n);
    }
    __syncthreads();
    const unsigned n = min(lcnt, BCAP);
    const unsigned gb = sbase;
    for (unsigned k = tid; k < n; k += 256) {
        const unsigned g = gb + k;
        if (g < CAND_CAP) { candI[g] = ci[k]; candB[g] = cb[k]; }
        else atomicExch(&scal[17], 1u);
    }
}

// ======== findfine_a: fine-bin of rank TOTK; zone bounds; validate ========
__global__ __launch_bounds__(1024) void findfine_a(const unsigned* __restrict__ fhist,
                                                   unsigned* __restrict__ scal)
{
    __shared__ unsigned fhl[FBINS];
    __shared__ unsigned tsum[1024];
    __shared__ unsigned suffix[1024];
    __shared__ unsigned sfb;
    const int t = threadIdx.x;
    fhl[t * 2] = fhist[t * 2];
    fhl[t * 2 + 1] = fhist[t * 2 + 1];
    tsum[t] = fhl[t * 2] + fhl[t * 2 + 1];
    if (t == 0) sfb = 0xFFFFFFFFu;
    __syncthreads();
    if (t == 0) {
        unsigned run = 0;
        for (int i = 1023; i >= 0; --i) { suffix[i] = run; run += tsum[i]; }
    }
    __syncthreads();
    const unsigned aboveBH = scal[16];
    unsigned cum = aboveBH + suffix[t];
    {
        const unsigned b1 = (unsigned)(t * 2 + 1);
        unsigned nb = cum + fhl[b1];
        if (cum < TOTK && nb >= TOTK) sfb = b1;
        cum = nb;
        const unsigned b0 = (unsigned)(t * 2);
        nb = cum + fhl[b0];
        if (cum < TOTK && nb >= TOTK) sfb = b0;
    }
    __syncthreads();
    if (t == 0) {
        const unsigned BLb = scal[20], BHb = scal[21];
        bool ok = (sfb != 0xFFFFFFFFu) && (scal[17] == 0u) && (scal[2] <= CAND_CAP);
        if (ok) {
            const int fs = fshift_calc(BLb, BHb);
            const unsigned flo = BLb + (sfb << fs);
            const unsigned fhi = BLb + ((sfb + 1u) << fs) - 1u;
            const float zLo = __uint_as_float(flo) - DELTA;
            const float zHi = __uint_as_float(fhi) + DELTA;
            const unsigned ZL = __float_as_uint(fmaxf(zLo, 1e-30f));
            const unsigned ZH = __float_as_uint(zHi);
            ok = ok && (ZL >= BLb);
            scal[6] = ZL;
            scal[7] = ZH;
        }
        scal[18] = ok ? 1u : 0u;
    }
}

// ======== findfine_b: multi-block above-zone count + zone gather ========
__global__ __launch_bounds__(256) void findfine_b(const unsigned* __restrict__ candB,
                                                  const unsigned* __restrict__ candI,
                                                  unsigned* __restrict__ scal,
                                                  unsigned* __restrict__ c2idx)
{
    if (!scal[18]) return;
    __shared__ unsigned lz[ZLOC_CAP];
    __shared__ unsigned red[256];
    __shared__ unsigned lcnt, sbase;
    const int tid = threadIdx.x;
    if (tid == 0) lcnt = 0;
    __syncthreads();
    const unsigned ZL = scal[6], ZH = scal[7];
    const unsigned C = min(scal[2], CAND_CAP);
    const unsigned stride = gridDim.x * blockDim.x;
    unsigned above = 0;
    for (unsigned i = blockIdx.x * blockDim.x + tid; i < C; i += stride) {
        const unsigned u = candB[i];
        if (u > ZH) above++;
        else if (u >= ZL) {
            const unsigned p = atomicAdd(&lcnt, 1u);
            if (p < ZLOC_CAP) lz[p] = candI[i];
        }
    }
    red[tid] = above;
    __syncthreads();
    for (int s = 128; s; s >>= 1) {
        if (tid < s) red[tid] += red[tid + s];
        __syncthreads();
    }
    if (tid == 0) {
        if (red[0]) atomicAdd(&scal[8], red[0]);
        const unsigned n = min(lcnt, ZLOC_CAP);
        if (lcnt > ZLOC_CAP) { atomicExch(&scal[17], 1u); atomicExch(&scal[18], 0u); }
        sbase = atomicAdd(&scal[9], n);
    }
    __syncthreads();
    const unsigned n = min(lcnt, ZLOC_CAP);
    const unsigned gb = sbase;
    for (unsigned k = tid; k < n; k += 256) {
        const unsigned g = gb + k;
        if (g < C2_CAP) c2idx[g] = lz[k];
        else { atomicExch(&scal[17], 1u); atomicExch(&scal[18], 0u); }
    }
}

// ============================================================================
// ============ fallback chain (round-9 proven; early-exit if OK) ============
// ============================================================================
__global__ __launch_bounds__(256) void fb_encode(
    const ushort* __restrict__ Ahi, const ushort* __restrict__ Bhi,
    const float* __restrict__ b_enc, float* __restrict__ feat,
    unsigned* __restrict__ fbhist, const unsigned* __restrict__ scal)
{
    if (scal[18]) return;
    __shared__ __align__(16) ushort As[128 * 64];
    __shared__ __align__(16) ushort Bs[128 * 64];
    __shared__ unsigned hls[NB2];
    const int tid = threadIdx.x;
    const int lane = tid & 63, wid = tid >> 6;
    const int flat = blockIdx.y * gridDim.x + blockIdx.x;
    const int swz = (flat & 7) * 512 + (flat >> 3);
    const int n0 = (swz & 127) * 128;
    const int m0 = (swz >> 7) * 128;
    const int wm = wid >> 1, wn = wid & 1;

    for (int i = tid; i < NB2; i += 256) hls[i] = 0;

    f32x4 acc[4][4];
#pragma unroll
    for (int i = 0; i < 4; ++i)
#pragma unroll
        for (int j = 0; j < 4; ++j) acc[i][j] = (f32x4){0.f, 0.f, 0.f, 0.f};

    const int srow = wid * 8 + (lane >> 3);
    const int schunk = (lane & 7) ^ (lane >> 3);
    const size_t abase = (size_t)(m0 + srow) * INDIM + schunk * 8;
    const size_t bbase = (size_t)(n0 + srow) * INDIM + schunk * 8;

    for (int t = 0; t < 16; ++t) {
        const int koff = t * 64;
#pragma unroll
        for (int i = 0; i < 4; ++i) {
            GL2LDS16(Ahi + abase + koff + (size_t)i * 32 * INDIM, &As[(i * 32 + wid * 8) * 64]);
            GL2LDS16(Bhi + bbase + koff + (size_t)i * 32 * INDIM, &Bs[(i * 32 + wid * 8) * 64]);
        }
        __syncthreads();
#pragma unroll
        for (int kq2 = 0; kq2 < 2; ++kq2) {
            short8 af[4], bf[4];
#pragma unroll
            for (int f = 0; f < 4; ++f) {
                const int ra = wm * 64 + f * 16 + (lane & 15);
                const int ca = (kq2 * 4 + (lane >> 4)) ^ (ra & 7);
                af[f] = *reinterpret_cast<const short8*>(&As[ra * 64 + ca * 8]);
                const int rb = wn * 64 + f * 16 + (lane & 15);
                const int cb = (kq2 * 4 + (lane >> 4)) ^ (rb & 7);
                bf[f] = *reinterpret_cast<const short8*>(&Bs[rb * 64 + cb * 8]);
            }
#pragma unroll
            for (int fm = 0; fm < 4; ++fm)
#pragma unroll
                for (int fn = 0; fn < 4; ++fn)
                    acc[fm][fn] = __builtin_amdgcn_mfma_f32_16x16x32_bf16(
                        af[fm], bf[fn], acc[fm][fn], 0, 0, 0);
        }
        __syncthreads();
    }

    const int crow0 = m0 + wm * 64;
    const int ccol0 = n0 + wn * 64;
#pragma unroll
    for (int fm = 0; fm < 4; ++fm) {
#pragma unroll
        for (int fn = 0; fn < 4; ++fn) {
            const int col = ccol0 + fn * 16 + (lane & 15);
            const float be = b_enc[col];
#pragma unroll
            for (int r = 0; r < 4; ++r) {
                const int row = crow0 + fm * 16 + (lane >> 4) * 4 + r;
                const float val = fmaxf(acc[fm][fn][r] + be, 0.f);
                feat[(size_t)row * DICT + col] = val;
                if (val > 0.f) atomicAdd(&hls[__float_as_uint(val) >> 19], 1u);
            }
        }
    }
    __syncthreads();
    unsigned* hdst = fbhist + (size_t)(flat & (HCOPIES - 1)) * NB2;
    for (int i = tid; i < NB2; i += 256)
        if (hls[i]) atomicAdd(&hdst[i], hls[i]);
}

__global__ __launch_bounds__(1024) void fb_findbin2(const unsigned* __restrict__ fbhist,
                                                    unsigned* __restrict__ scal)
{
    if (scal[18]) return;
    __shared__ unsigned tot[NB2];
    __shared__ unsigned tsum[1024];
    __shared__ unsigned suffix[1024];
    const int t = threadIdx.x;
    if (t == 0) { scal[9] = 0; scal[8] = 0; }   // reset pollution from aborted primary
    unsigned s = 0;
#pragma unroll
    for (int i = 0; i < 4; ++i) {
        const int b = t * 4 + i;
        unsigned v = 0;
        for (int c = 0; c < HCOPIES; ++c) v += fbhist[(size_t)c * NB2 + b];
        tot[b] = v;
        s += v;
    }
    tsum[t] = s;
    __syncthreads();
    if (t == 0) {
        unsigned run = 0;
        for (int i = 1023; i >= 0; --i) { suffix[i] = run; run += tsum[i]; }
    }
    __syncthreads();
    unsigned cum = suffix[t];
    for (int i = 3; i >= 0; --i) {
        const unsigned b = (unsigned)(t * 4 + i);
        const unsigned nb = cum + tot[b];
        if (cum < TOTK && nb >= TOTK) {
            scal[0] = b;
            scal[1] = cum;
            scal[10] = cum - ((b + 1 < NB2) ? tot[b + 1] : 0u);
        }
        cum = nb;
    }
}

__global__ __launch_bounds__(256) void fb_collectC(const float* __restrict__ feat,
                                                   unsigned* __restrict__ scal,
                                                   unsigned* __restrict__ candI,
                                                   unsigned* __restrict__ candB,
                                                   unsigned* __restrict__ h1)
{
    if (scal[18]) return;
    __shared__ unsigned lidx[CLOC_CAP];
    __shared__ unsigned lbits[CLOC_CAP];
    __shared__ unsigned lcnt;
    __shared__ unsigned sbase;
    const int tid = threadIdx.x;
    if (tid == 0) lcnt = 0;
    __syncthreads();
    const unsigned b = scal[0];
    const unsigned lob = (b > 0 ? b - 1 : b) << 19;
    const unsigned hib = ((b + 2 < NB2) ? (b + 2) : NB2) << 19;
    const size_t stride = (size_t)gridDim.x * blockDim.x * 4;
    size_t base = ((size_t)blockIdx.x * blockDim.x + tid) * 4;
    for (size_t i = base; i < NFEAT; i += stride) {
        const float4 v = *reinterpret_cast<const float4*>(&feat[i]);
        const unsigned u[4] = {__float_as_uint(v.x), __float_as_uint(v.y),
                               __float_as_uint(v.z), __float_as_uint(v.w)};
#pragma unroll
        for (int q = 0; q < 4; ++q) {
            if (u[q] != 0u && u[q] >= lob && u[q] < hib) {
                const unsigned p = atomicAdd(&lcnt, 1u);
                if (p < CLOC_CAP) { lidx[p] = (unsigned)(i + q); lbits[p] = u[q]; }
                if ((u[q] >> 19) == b) atomicAdd(&h1[(u[q] >> 9) & 1023u], 1u);
            }
        }
    }
    __syncthreads();
    const unsigned n = min(lcnt, (unsigned)CLOC_CAP);
    if (tid == 0) sbase = atomicAdd(&scal[24], n);
    __syncthreads();
    const unsigned gb = sbase;
    for (unsigned k = tid; k < n; k += 256) {
        const unsigned g = gb + k;
        if (g < CAND_CAP) { candI[g] = lidx[k]; candB[g] = lbits[k]; }
    }
}

__global__ __launch_bounds__(1024) void fb_selectZ(const unsigned* __restrict__ h1,
                                                   const unsigned* __restrict__ candB,
                                                   const unsigned* __restrict__ candI,
                                                   unsigned* __restrict__ scal,
                                                   unsigned* __restrict__ c2idx)
{
    if (scal[18]) return;
    __shared__ unsigned h[1024];
    __shared__ unsigned cnt[1024];
    const int t = threadIdx.x;
    h[t] = h1[t];
    __syncthreads();
    if (t == 0) {
        const unsigned b = scal[0];
        unsigned cum = scal[1];
        unsigned s = 0;
        for (int i = 1023; i >= 0; --i) {
            const unsigned nb = cum + h[i];
            if (cum < TOTK && nb >= TOTK) s = (unsigned)i;
            cum = nb;
        }
        const float slo = __uint_as_float((b << 19) | (s << 9));
        const float shi = __uint_as_float((b << 19) | (s << 9) | 0x1FFu);
        scal[6] = __float_as_uint(fmaxf(slo - DELTA, 1e-30f));
        scal[7] = __float_as_uint(shi + DELTA);
    }
    __syncthreads();
    const float ZLf = __uint_as_float(scal[6]);
    const float ZHf = __uint_as_float(scal[7]);
    const unsigned C = min(scal[24], CAND_CAP);
    unsigned above = 0;
    for (unsigned i = t; i < C; i += 1024) {
        const float v = __uint_as_float(candB[i]);
        if (v > ZHf) above++;
        else if (v >= ZLf) {
            const unsigned p = atomicAdd(&scal[9], 1u);
            if (p < C2_CAP) c2idx[p] = candI[i];
        }
    }
    cnt[t] = above;
    __syncthreads();
    for (int s2 = 512; s2; s2 >>= 1) {
        if (t < s2) cnt[t] += cnt[t + s2];
        __syncthreads();
    }
    if (t == 0) scal[8] = scal[10] + cnt[0];
}

// ====== exact OpenBLAS-mimic recompute of zone candidates (shared) ======
__global__ __launch_bounds__(256) void refine2_kernel(
    const float* __restrict__ x, const float* __restrict__ W,
    const float* __restrict__ b_enc, const float* __restrict__ b_dec,
    const unsigned* __restrict__ scal, const unsigned* __restrict__ c2idx,
    float* __restrict__ c2val)
{
    const unsigned n = min(scal[9], C2_CAP);
    const size_t stride = (size_t)gridDim.x * blockDim.x;
    for (unsigned c = blockIdx.x * blockDim.x + threadIdx.x; c < n; c += stride) {
        const unsigned i = c2idx[c];
        const int m = (int)(i >> 14);
        const int d = (int)(i & (DICT - 1));
        const float* xr = x + (size_t)m * INDIM;
        const float* wr = W + (size_t)d * INDIM;
        const int kb[4] = {0, 384, 704, 1024};
        float tot = 0.f;
        for (int p = 0; p < 3; ++p) {
            float a = 0.f;
#pragma unroll 8
            for (int k = kb[p]; k < kb[p + 1]; ++k)
                a = fmaf(xr[k] - b_dec[k], wr[k], a);
            tot = (p == 0) ? a : (tot + a);
        }
        c2val[c] = tot + b_enc[d];
    }
}

// ====== zone order-statistic: hist + find vj in ONE kernel ======
__device__ inline int zone_shift(unsigned ZL, unsigned ZH) {
    const unsigned range = ZH - ZL + 1u;
    int shift = 0;
    while ((range >> shift) > (unsigned)ZBINS) ++shift;
    return shift;
}

__global__ __launch_bounds__(1024) void findv_kernel(const float* __restrict__ c2val,
                                                     unsigned* __restrict__ scal)
{
    __shared__ unsigned h[ZBINS];
    __shared__ float mem[1024];
    __shared__ unsigned mcnt;
    __shared__ unsigned sbsel, sjj;
    const int t = threadIdx.x;
    h[t] = 0;
    h[t + 1024] = 0;
    if (t == 0) mcnt = 0;
    __syncthreads();
    const unsigned n = min(scal[9], C2_CAP);
    const unsigned ZL = scal[6], ZH = scal[7];
    const int shift = zone_shift(ZL, ZH);
    for (unsigned i = t; i < n; i += 1024) {
        const unsigned bits = __float_as_uint(c2val[i]);
        const unsigned idx = (bits <= ZL) ? 0u : min((unsigned)(ZBINS - 1), (bits - ZL) >> shift);
        atomicAdd(&h[idx], 1u);
    }
    __syncthreads();
    unsigned j = TOTK - scal[8];
    if (j > n) j = n;
    if (t == 0) {
        unsigned cum = 0, bsel = 0, jj = j;
        for (int i = ZBINS - 1; i >= 0; --i) {
            const unsigned nb = cum + h[i];
            if (cum < j && nb >= j) { bsel = (unsigned)i; jj = j - cum; }
            cum = nb;
        }
        sbsel = bsel; sjj = jj;
    }
    __syncthreads();
    const unsigned bsel = sbsel, jj = sjj;
    for (unsigned i = t; i < n; i += 1024) {
        const unsigned bits = __float_as_uint(c2val[i]);
        const unsigned idx = (bits <= ZL) ? 0u : min((unsigned)(ZBINS - 1), (bits - ZL) >> shift);
        if (idx == bsel) {
            const unsigned p = atomicAdd(&mcnt, 1u);
            if (p < 1024) mem[p] = c2val[i];
        }
    }
    __syncthreads();
    const unsigned m = min(mcnt, 1024u);
    for (unsigned i = t; i < m; i += 1024) {
        const float v = mem[i];
        unsigned g = 0, eq = 0;
        for (unsigned d = 0; d < m; ++d) {
            g += (mem[d] > v) ? 1u : 0u;
            eq += (mem[d] == v) ? 1u : 0u;
        }
        if (g < jj && g + eq >= jj) scal[11] = __float_as_uint(v);
    }
}

// ====== keephash: FALLBACK ONLY (primary uses scatter_all directly) ======
__global__ __launch_bounds__(256) void keephash_kernel(const unsigned* __restrict__ scal,
                                                       const unsigned* __restrict__ c2idx,
                                                       const float* __restrict__ c2val,
                                                       uint2* __restrict__ hash)
{
    if (scal[18]) return;
    const unsigned n = min(scal[9], C2_CAP);
    const float vj = __uint_as_float(scal[11]);
    const unsigned stride = gridDim.x * blockDim.x;
    for (unsigned i = blockIdx.x * blockDim.x + threadIdx.x; i < n; i += stride) {
        const float v = c2val[i];
        if (v >= vj) {
            const unsigned key = c2idx[i];
            unsigned s = (key * 2654435761u) & (HASH_SZ - 1);
            while (atomicCAS(&hash[s].x, 0xFFFFFFFFu, key) != 0xFFFFFFFFu)
                s = (s + 1) & (HASH_SZ - 1);
            hash[s].y = __float_as_uint(v);
        }
    }
}

// ============ transpose W_dec -> Wt(bf16) [DICT][INDIM] ============
__global__ void transpose_kernel(const float* __restrict__ W, ushort* __restrict__ Wt)
{
    __shared__ float t[32][33];
    const int x0 = blockIdx.x * 32;
    const int y0 = blockIdx.y * 32;
    const int tx = threadIdx.x, ty = threadIdx.y;
    for (int r = ty; r < 32; r += 8)
        t[r][tx] = W[(size_t)(y0 + r) * DICT + x0 + tx];
    __syncthreads();
    for (int r = ty; r < 32; r += 8)
        Wt[(size_t)(x0 + r) * INDIM + y0 + tx] = bf16_rne_u(t[tx][r]);
}

// ====== primary: scatter kept (above-zone approx + in-zone exact) ======
__global__ __launch_bounds__(256) void scatter_all(
    unsigned* __restrict__ scal, const unsigned* __restrict__ candI,
    const unsigned* __restrict__ candB, const unsigned* __restrict__ c2idx,
    const float* __restrict__ c2val,
    float* __restrict__ feat, uint2* __restrict__ entries,
    unsigned* __restrict__ rowcnt)
{
    if (!scal[18]) return;
    __shared__ unsigned red[256];
    const unsigned stride = gridDim.x * blockDim.x;
    unsigned kept = 0;
    // above-zone candidates (approx stored value)
    {
        const unsigned C = min(scal[2], CAND_CAP);
        const unsigned ZH = scal[7];
        for (unsigned i = blockIdx.x * blockDim.x + threadIdx.x; i < C; i += stride) {
            const unsigned u = candB[i];
            if (u > ZH) {
                const unsigned idx = candI[i];
                feat[idx] = __uint_as_float(u);
                const unsigned row = idx >> 14;
                const unsigned p = atomicAdd(&rowcnt[row], 1u);
                if (p < ROW_CAP)
                    entries[(size_t)row * ROW_CAP + p] = make_uint2(idx & (DICT - 1), u);
                kept++;
            }
        }
    }
    // in-zone kept (exact values, v >= vj)
    {
        const unsigned n = min(scal[9], C2_CAP);
        const float vj = __uint_as_float(scal[11]);
        for (unsigned i = blockIdx.x * blockDim.x + threadIdx.x; i < n; i += stride) {
            const float v = c2val[i];
            if (v >= vj) {
                const unsigned idx = c2idx[i];
                feat[idx] = v;
                const unsigned row = idx >> 14;
                const unsigned p = atomicAdd(&rowcnt[row], 1u);
                if (p < ROW_CAP)
                    entries[(size_t)row * ROW_CAP + p] =
                        make_uint2(idx & (DICT - 1), __float_as_uint(v));
                kept++;
            }
        }
    }
    red[threadIdx.x] = kept;
    __syncthreads();
    for (int s = 128; s; s >>= 1) {
        if (threadIdx.x < s) red[threadIdx.x] += red[threadIdx.x + s];
        __syncthreads();
    }
    if (threadIdx.x == 0 && red[0]) atomicAdd(&scal[4], red[0]);
}

// ====== primary: decode from per-row lists (bf16 Wt, no feat read) ======
__global__ __launch_bounds__(256) void decode2_kernel(
    const unsigned* __restrict__ scal, const uint2* __restrict__ entries,
    const unsigned* __restrict__ rowcnt, const ushort* __restrict__ Wt,
    const float* __restrict__ b_dec, const float* __restrict__ x,
    float* __restrict__ recon, double* __restrict__ loss_sum)
{
    if (!scal[18]) return;
    __shared__ uint2 lst[ROW_CAP];
    __shared__ double redd[256];
    const int row = blockIdx.x;
    const int tid = threadIdx.x;
    const unsigned n = min(rowcnt[row], (unsigned)ROW_CAP);
    for (unsigned i = tid; i < n; i += 256) lst[i] = entries[(size_t)row * ROW_CAP + i];
    __syncthreads();
    float4 acc = make_float4(0.f, 0.f, 0.f, 0.f);
    for (unsigned e = 0; e < n; ++e) {
        const uint2 en = lst[e];
        const float v = __uint_as_float(en.y);
        const ushort4 w4 = *reinterpret_cast<const ushort4*>(Wt + (size_t)en.x * INDIM + tid * 4);
        acc.x = fmaf(v, bf16_to_f(w4.x), acc.x);
        acc.y = fmaf(v, bf16_to_f(w4.y), acc.y);
        acc.z = fmaf(v, bf16_to_f(w4.z), acc.z);
        acc.w = fmaf(v, bf16_to_f(w4.w), acc.w);
    }
    const float4 bd = reinterpret_cast<const float4*>(b_dec)[tid];
    acc.x += bd.x; acc.y += bd.y; acc.z += bd.z; acc.w += bd.w;
    reinterpret_cast<float4*>(recon + (size_t)row * INDIM)[tid] = acc;
    const float4 xv = reinterpret_cast<const float4*>(x + (size_t)row * INDIM)[tid];
    const double d0 = (double)acc.x - (double)xv.x;
    const double d1 = (double)acc.y - (double)xv.y;
    const double d2 = (double)acc.z - (double)xv.z;
    const double d3 = (double)acc.w - (double)xv.w;
    redd[tid] = d0 * d0 + d1 * d1 + d2 * d2 + d3 * d3;
    __syncthreads();
    for (int s = 128; s; s >>= 1) {
        if (tid < s) redd[tid] += redd[tid + s];
        __syncthreads();
    }
    if (tid == 0) atomicAdd(loss_sum, redd[0]);
}

// ====== fallback: mask feat + decode (bf16 Wt) ======
__global__ __launch_bounds__(256) void fb_compact_decode(
    float* __restrict__ feat, unsigned* __restrict__ scal,
    const uint2* __restrict__ hash, const ushort* __restrict__ Wt,
    const float* __restrict__ b_dec, const float* __restrict__ x,
    float* __restrict__ recon, double* __restrict__ loss_sum)
{
    if (scal[18]) return;
    __shared__ uint2 lst[ROW_CAP];
    __shared__ unsigned cnt;
    __shared__ double redd[256];
    const int row = blockIdx.x;
    const int tid = threadIdx.x;
    if (tid == 0) cnt = 0;
    __syncthreads();
    const float ZLf = __uint_as_float(scal[6]);
    const float ZHf = __uint_as_float(scal[7]);
    float* frow = feat + (size_t)row * DICT;
#pragma unroll
    for (int it = 0; it < DICT / 4 / 256; ++it) {
        const int i4 = it * 256 + tid;
        float4 v = reinterpret_cast<float4*>(frow)[i4];
        float a[4] = {v.x, v.y, v.z, v.w};
        float out[4] = {0.f, 0.f, 0.f, 0.f};
#pragma unroll
        for (int q = 0; q < 4; ++q) {
            const float val = a[q];
            if (val > ZHf) {
                out[q] = val;
            } else if (val >= ZLf && val > 0.f) {
                const unsigned key = (unsigned)(row * DICT + i4 * 4 + q);
                unsigned s = (key * 2654435761u) & (HASH_SZ - 1);
                while (true) {
                    const uint2 e = hash[s];
                    if (e.x == key) { out[q] = __uint_as_float(e.y); break; }
                    if (e.x == 0xFFFFFFFFu) break;
                    s = (s + 1) & (HASH_SZ - 1);
                }
            }
            if (out[q] != 0.f) {
                const unsigned p = atomicAdd(&cnt, 1u);
                if (p < ROW_CAP)
                    lst[p] = make_uint2((unsigned)(i4 * 4 + q), __float_as_uint(out[q]));
            }
        }
        reinterpret_cast<float4*>(frow)[i4] = make_float4(out[0], out[1], out[2], out[3]);
    }
    __syncthreads();
    const unsigned n = min(cnt, (unsigned)ROW_CAP);
    float4 acc = make_float4(0.f, 0.f, 0.f, 0.f);
    for (unsigned e = 0; e < n; ++e) {
        const uint2 en = lst[e];
        const float v = __uint_as_float(en.y);
        const ushort4 w4 = *reinterpret_cast<const ushort4*>(Wt + (size_t)en.x * INDIM + tid * 4);
        acc.x = fmaf(v, bf16_to_f(w4.x), acc.x);
        acc.y = fmaf(v, bf16_to_f(w4.y), acc.y);
        acc.z = fmaf(v, bf16_to_f(w4.z), acc.z);
        acc.w = fmaf(v, bf16_to_f(w4.w), acc.w);
    }
    const float4 bd = reinterpret_cast<const float4*>(b_dec)[tid];
    acc.x += bd.x; acc.y += bd.y; acc.z += bd.z; acc.w += bd.w;
    reinterpret_cast<float4*>(recon + (size_t)row * INDIM)[tid] = acc;
    const float4 xv = reinterpret_cast<const float4*>(x + (size_t)row * INDIM)[tid];
    const double d0 = (double)acc.x - (double)xv.x;
    const double d1 = (double)acc.y - (double)xv.y;
    const double d2 = (double)acc.z - (double)xv.z;
    const double d3 = (double)acc.w - (double)xv.w;
    redd[tid] = d0 * d0 + d1 * d1 + d2 * d2 + d3 * d3;
    __syncthreads();
    for (int s = 128; s; s >>= 1) {
        if (tid < s) redd[tid] += redd[tid + s];
        __syncthreads();
    }
    if (tid == 0) {
        atomicAdd(loss_sum, redd[0]);
        if (cnt) atomicAdd(&scal[4], cnt);
    }
}

__global__ void finalize_kernel(const unsigned* __restrict__ scal, float* __restrict__ tail)
{
    const double* loss_d = reinterpret_cast<const double*>(&scal[12]);
    const float rec = (float)(loss_d[0] / (double)((size_t)BATCH * INDIM));
    tail[0] = rec;
    tail[1] = rec;
    tail[2] = 0.f;
    tail[3] = (float)scal[4] / (float)BATCH;
}

extern "C" void kernel_launch(void* const* d_in, const int* in_sizes, int n_in,
                              void* d_out, int out_size, void* d_ws, size_t ws_size,
                              hipStream_t stream)
{
    const float* x     = (const float*)d_in[0];
    const float* W_enc = (const float*)d_in[1];
    const float* b_enc = (const float*)d_in[2];
    const float* W_dec = (const float*)d_in[3];
    const float* b_dec = (const float*)d_in[4];

    float* recon = (float*)d_out;
    float* feat  = recon + (size_t)BATCH * INDIM;
    float* tail  = feat + NFEAT;

    unsigned* pshist = (unsigned*)((char*)d_ws + PSH_OFF);
    unsigned* fhist  = (unsigned*)((char*)d_ws + FH_OFF);
    unsigned* scal   = (unsigned*)((char*)d_ws + SCAL_OFF);
    unsigned* h1     = (unsigned*)((char*)d_ws + H1_OFF);
    unsigned* rowcnt = (unsigned*)((char*)d_ws + ROWC_OFF);
    uint2*    hash   = (uint2*)   ((char*)d_ws + HASH_OFF);
    unsigned* fbhist = (unsigned*)((char*)d_ws + FBH_OFF);
    unsigned* candI  = (unsigned*)((char*)d_ws + CANDI_OFF);
    unsigned* candB  = (unsigned*)((char*)d_ws + CANDB_OFF);
    unsigned* c2idx  = (unsigned*)((char*)d_ws + C2I_OFF);
    float*    c2val  = (float*)   ((char*)d_ws + C2V_OFF);
    uint2*    entries= (uint2*)   ((char*)d_ws + ENT_OFF);
    ushort*   Ahi    = (ushort*)  ((char*)d_ws + AHI_OFF);
    ushort*   Bhi    = (ushort*)  ((char*)d_ws + BHI_OFF);
    ushort*   Wt     = (ushort*)  ((char*)d_ws + WT_OFF);
    double*   loss_sum = (double*)&scal[12];

    hipMemsetAsync(d_ws, 0, MEMSET0, stream);                     // hists/scal/rowcnt/fbhist
    hipMemsetAsync((char*)d_ws + HASH_OFF, 0xFF, HASH_SZ * sizeof(uint2), stream);

    split_kernel<<<2048, 256, 0, stream>>>(x, W_enc, b_dec, Ahi, Bhi);
    presample_mfma<<<128, 256, 0, stream>>>(Ahi, Bhi, b_enc, pshist);
    presample_find<<<1, 1024, 0, stream>>>(pshist, scal);
    encode_main<<<dim3(128, 32), 256, 0, stream>>>(Ahi, Bhi, b_enc, scal, fhist, candI, candB, feat);
    findfine_a<<<1, 1024, 0, stream>>>(fhist, scal);
    findfine_b<<<256, 256, 0, stream>>>(candB, candI, scal, c2idx);

    // fallback chain (early-exit when primary validated OK)
    fb_encode<<<dim3(128, 32), 256, 0, stream>>>(Ahi, Bhi, b_enc, feat, fbhist, scal);
    fb_findbin2<<<1, 1024, 0, stream>>>(fbhist, scal);
    fb_collectC<<<1024, 256, 0, stream>>>(feat, scal, candI, candB, h1);
    fb_selectZ<<<1, 1024, 0, stream>>>(h1, candB, candI, scal, c2idx);

    // shared exact-ranking machinery
    refine2_kernel<<<128, 256, 0, stream>>>(x, W_enc, b_enc, b_dec, scal, c2idx, c2val);
    findv_kernel<<<1, 1024, 0, stream>>>(c2val, scal);
    keephash_kernel<<<64, 256, 0, stream>>>(scal, c2idx, c2val, hash);   // fallback-only

    transpose_kernel<<<dim3(DICT / 32, INDIM / 32), dim3(32, 8), 0, stream>>>(W_dec, Wt);

    // primary finish
    scatter_all<<<256, 256, 0, stream>>>(scal, candI, candB, c2idx, c2val, feat, entries, rowcnt);
    decode2_kernel<<<BATCH, 256, 0, stream>>>(scal, entries, rowcnt, Wt, b_dec, x, recon, loss_sum);
    // fallback finish
    fb_compact_decode<<<BATCH, 256, 0, stream>>>(feat, scal, hash, Wt, b_dec, x, recon, loss_sum);

    finalize_kernel<<<1, 1, 0, stream>>>(scal, tail);
}

// Round 17
// 566.928 us; speedup vs baseline: 1.0232x; 1.0232x over previous
//
#include <hip/hip_runtime.h>
#include <cstdint>
#include <cstddef>

#define BATCH   4096
#define INDIM   1024
#define DICT    16384
#define TOTK    (32 * 4096)
#define NFEAT   ((size_t)BATCH * DICT)   // 67108864
#define DELTA   3e-2f                    // zone half-width; >= 2*maxerr(hi*hi GEMM)
#define BAND    0.2f                     // presample band margin
#define PS_RANK (TOTK / 32)              // rank in 128-row sample (1/32 of batch)

#define NB2       4096            // coarse bins (u >> 19)
#define FBINS     2048            // fine-hist bins over [BL,BH)
#define CAND_CAP  (1u << 19)
#define BCAP      256u            // per-block candidate cap (avg ~52)
#define ZLOC_CAP  2048u           // per-block in-zone cap in findfine_b
#define C2_CAP    65536u
#define ROW_CAP   512
#define ZBINS     2048

// ---- ws layout ----
// [0,16K) pshist | [16K,24K) fhist | [32K,+256) scal | [40K,56K) rowcnt |
// [2M,4M) candI | [4M,6M) candB | [6M,+256K) c2idx | [6M+256K,+256K) c2val |
// [7M,23M) entries | [24M,32M) Ahi | [32M,64M) Bhi |
// Wt(bf16,32M) overlays [24M,56M) after encode_main
// scal: 2=candCnt,4=l0,6=ZL,7=ZH,8=aboveZone,9=c2cnt,11=vj,
//       12..13=loss(f64),16=aboveBH,17=ovf,18=OK,20=BLbits,21=BHbits
#define PSH_OFF   0ull
#define FH_OFF    16384ull
#define SCAL_OFF  32768ull
#define ROWC_OFF  40960ull
#define MEMSET0   57344ull
#define CANDI_OFF (2ull << 20)
#define CANDB_OFF (4ull << 20)
#define C2I_OFF   (6ull << 20)
#define C2V_OFF   ((6ull << 20) + 262144)
#define ENT_OFF   (7ull << 20)
#define AHI_OFF   (24ull << 20)
#define BHI_OFF   (32ull << 20)
#define WT_OFF    (24ull << 20)
#define WS_NEED   (88ull << 20)

typedef __attribute__((ext_vector_type(8))) short short8;
typedef __attribute__((ext_vector_type(4))) float f32x4;

#define GL2LDS16(g, l) __builtin_amdgcn_global_load_lds( \
    (const __attribute__((address_space(1))) void*)(g), \
    (__attribute__((address_space(3))) void*)(l), 16, 0, 0)

__device__ inline ushort bf16_rne_u(float a) {
    unsigned u = __float_as_uint(a);
    return (ushort)((u + 0x7FFFu + ((u >> 16) & 1u)) >> 16);
}

__device__ inline float bf16_to_f(ushort u) {
    return __uint_as_float(((unsigned)u) << 16);
}

__device__ inline int fshift_calc(unsigned BL, unsigned BH) {
    const unsigned range = BH - BL;
    int s = 0;
    while ((range >> s) > (unsigned)FBINS) ++s;
    return s;
}

// ======== split: Ahi = bf16(x - b_dec), Bhi = bf16(W_enc) ========
__global__ __launch_bounds__(256) void split_kernel(
    const float* __restrict__ x, const float* __restrict__ W,
    const float* __restrict__ b_dec,
    ushort* __restrict__ Ahi, ushort* __restrict__ Bhi)
{
    const size_t NA = (size_t)BATCH * INDIM / 4;
    const size_t NB = (size_t)DICT * INDIM / 4;
    const size_t stride = (size_t)gridDim.x * blockDim.x;
    for (size_t i = (size_t)blockIdx.x * blockDim.x + threadIdx.x; i < NA + NB; i += stride) {
        float4 v;
        ushort* hp;
        if (i < NA) {
            v = reinterpret_cast<const float4*>(x)[i];
            const float4 bd = reinterpret_cast<const float4*>(b_dec)[i & (INDIM / 4 - 1)];
            v.x -= bd.x; v.y -= bd.y; v.z -= bd.z; v.w -= bd.w;
            hp = Ahi + i * 4;
        } else {
            v = reinterpret_cast<const float4*>(W)[i - NA];
            hp = Bhi + (i - NA) * 4;
        }
        ushort4 h;
        h.x = bf16_rne_u(v.x);
        h.y = bf16_rne_u(v.y);
        h.z = bf16_rne_u(v.z);
        h.w = bf16_rne_u(v.w);
        *reinterpret_cast<ushort4*>(hp) = h;
    }
}

// ======== presample: rows 0..127, all cols; coarse hist only ========
__global__ __launch_bounds__(256) void presample_mfma(
    const ushort* __restrict__ Ahi, const ushort* __restrict__ Bhi,
    const float* __restrict__ b_enc, unsigned* __restrict__ pshist)
{
    __shared__ __align__(16) ushort As[128 * 64];
    __shared__ __align__(16) ushort Bs[128 * 64];
    __shared__ unsigned hls[NB2];
    const int tid = threadIdx.x;
    const int lane = tid & 63, wid = tid >> 6;
    const int n0 = blockIdx.x * 128;
    const int m0 = 0;
    const int wm = wid >> 1, wn = wid & 1;

    for (int i = tid; i < NB2; i += 256) hls[i] = 0;

    f32x4 acc[4][4];
#pragma unroll
    for (int i = 0; i < 4; ++i)
#pragma unroll
        for (int j = 0; j < 4; ++j) acc[i][j] = (f32x4){0.f, 0.f, 0.f, 0.f};

    const int srow = wid * 8 + (lane >> 3);
    const int schunk = (lane & 7) ^ (lane >> 3);
    const size_t abase = (size_t)(m0 + srow) * INDIM + schunk * 8;
    const size_t bbase = (size_t)(n0 + srow) * INDIM + schunk * 8;

    for (int t = 0; t < 16; ++t) {
        const int koff = t * 64;
#pragma unroll
        for (int i = 0; i < 4; ++i) {
            GL2LDS16(Ahi + abase + koff + (size_t)i * 32 * INDIM, &As[(i * 32 + wid * 8) * 64]);
            GL2LDS16(Bhi + bbase + koff + (size_t)i * 32 * INDIM, &Bs[(i * 32 + wid * 8) * 64]);
        }
        __syncthreads();
#pragma unroll
        for (int kq2 = 0; kq2 < 2; ++kq2) {
            short8 af[4], bf[4];
#pragma unroll
            for (int f = 0; f < 4; ++f) {
                const int ra = wm * 64 + f * 16 + (lane & 15);
                const int ca = (kq2 * 4 + (lane >> 4)) ^ (ra & 7);
                af[f] = *reinterpret_cast<const short8*>(&As[ra * 64 + ca * 8]);
                const int rb = wn * 64 + f * 16 + (lane & 15);
                const int cb = (kq2 * 4 + (lane >> 4)) ^ (rb & 7);
                bf[f] = *reinterpret_cast<const short8*>(&Bs[rb * 64 + cb * 8]);
            }
#pragma unroll
            for (int fm = 0; fm < 4; ++fm)
#pragma unroll
                for (int fn = 0; fn < 4; ++fn)
                    acc[fm][fn] = __builtin_amdgcn_mfma_f32_16x16x32_bf16(
                        af[fm], bf[fn], acc[fm][fn], 0, 0, 0);
        }
        __syncthreads();
    }

    const int ccol0 = n0 + wn * 64;
#pragma unroll
    for (int fm = 0; fm < 4; ++fm) {
#pragma unroll
        for (int fn = 0; fn < 4; ++fn) {
            const int col = ccol0 + fn * 16 + (lane & 15);
            const float be = b_enc[col];
#pragma unroll
            for (int r = 0; r < 4; ++r) {
                const float val = fmaxf(acc[fm][fn][r] + be, 0.f);
                if (val > 0.f) atomicAdd(&hls[__float_as_uint(val) >> 19], 1u);
            }
        }
    }
    __syncthreads();
    for (int i = tid; i < NB2; i += 256)
        if (hls[i]) atomicAdd(&pshist[i], hls[i]);
}

// ======== presample_find: coarse bin of sample rank -> band [BL,BH] ========
__global__ __launch_bounds__(1024) void presample_find(const unsigned* __restrict__ pshist,
                                                       unsigned* __restrict__ scal)
{
    __shared__ unsigned tot[NB2];
    __shared__ unsigned tsum[1024];
    __shared__ unsigned suffix[1024];
    const int t = threadIdx.x;
    unsigned s = 0;
#pragma unroll
    for (int i = 0; i < 4; ++i) {
        const int b = t * 4 + i;
        const unsigned v = pshist[b];
        tot[b] = v;
        s += v;
    }
    tsum[t] = s;
    __syncthreads();
    if (t == 0) {
        unsigned run = 0;
        for (int i = 1023; i >= 0; --i) { suffix[i] = run; run += tsum[i]; }
    }
    __syncthreads();
    unsigned cum = suffix[t];
    for (int i = 3; i >= 0; --i) {
        const unsigned b = (unsigned)(t * 4 + i);
        const unsigned nb = cum + tot[b];
        if (cum < PS_RANK && nb >= PS_RANK) {
            const float blo = __uint_as_float(b << 19);
            const float bhi = __uint_as_float((b + 1) << 19);
            scal[20] = __float_as_uint(fmaxf(blo - BAND, 1e-30f));
            scal[21] = __float_as_uint(bhi + BAND);
        }
        cum = nb;
    }
}

// ======== encode_main: MFMA + candidate emit + fine hist + vector zero-fill ========
__global__ __launch_bounds__(256) void encode_main(
    const ushort* __restrict__ Ahi, const ushort* __restrict__ Bhi,
    const float* __restrict__ b_enc, unsigned* __restrict__ scal,
    unsigned* __restrict__ fhist, unsigned* __restrict__ candI,
    unsigned* __restrict__ candB, float* __restrict__ feat)
{
    __shared__ __align__(16) ushort As[128 * 64];
    __shared__ __align__(16) ushort Bs[128 * 64];
    __shared__ unsigned ci[BCAP];
    __shared__ unsigned cb[BCAP];
    __shared__ unsigned lcnt, labv, sbase;
    const int tid = threadIdx.x;
    const int lane = tid & 63, wid = tid >> 6;
    // XCD slab ordering: 16 n-tiles per XCD (4MB B in L2), m cycles slowest
    const int flat = blockIdx.y * gridDim.x + blockIdx.x;
    const int n0 = ((flat & 7) * 16 + ((flat >> 3) & 15)) * 128;
    const int m0 = (flat >> 7) * 128;
    const int wm = wid >> 1, wn = wid & 1;

    if (tid == 0) { lcnt = 0; labv = 0; }

    const unsigned BLb = scal[20], BHb = scal[21];
    const float BLf = __uint_as_float(BLb);
    const int fs = fshift_calc(BLb, BHb);

    f32x4 acc[4][4];
#pragma unroll
    for (int i = 0; i < 4; ++i)
#pragma unroll
        for (int j = 0; j < 4; ++j) acc[i][j] = (f32x4){0.f, 0.f, 0.f, 0.f};

    const int srow = wid * 8 + (lane >> 3);
    const int schunk = (lane & 7) ^ (lane >> 3);
    const size_t abase = (size_t)(m0 + srow) * INDIM + schunk * 8;
    const size_t bbase = (size_t)(n0 + srow) * INDIM + schunk * 8;

    for (int t = 0; t < 16; ++t) {
        const int koff = t * 64;
#pragma unroll
        for (int i = 0; i < 4; ++i) {
            GL2LDS16(Ahi + abase + koff + (size_t)i * 32 * INDIM, &As[(i * 32 + wid * 8) * 64]);
            GL2LDS16(Bhi + bbase + koff + (size_t)i * 32 * INDIM, &Bs[(i * 32 + wid * 8) * 64]);
        }
        __syncthreads();
#pragma unroll
        for (int kq2 = 0; kq2 < 2; ++kq2) {
            short8 af[4], bf[4];
#pragma unroll
            for (int f = 0; f < 4; ++f) {
                const int ra = wm * 64 + f * 16 + (lane & 15);
                const int ca = (kq2 * 4 + (lane >> 4)) ^ (ra & 7);
                af[f] = *reinterpret_cast<const short8*>(&As[ra * 64 + ca * 8]);
                const int rb = wn * 64 + f * 16 + (lane & 15);
                const int cbx = (kq2 * 4 + (lane >> 4)) ^ (rb & 7);
                bf[f] = *reinterpret_cast<const short8*>(&Bs[rb * 64 + cbx * 8]);
            }
#pragma unroll
            for (int fm = 0; fm < 4; ++fm)
#pragma unroll
                for (int fn = 0; fn < 4; ++fn)
                    acc[fm][fn] = __builtin_amdgcn_mfma_f32_16x16x32_bf16(
                        af[fm], bf[fn], acc[fm][fn], 0, 0, 0);
        }
        __syncthreads();
    }

    // ---- plain vectorized zero-fill of this block's 128x128 tile ----
    {
        const f32x4 z = (f32x4){0.f, 0.f, 0.f, 0.f};
        f32x4* trow = reinterpret_cast<f32x4*>(feat + (size_t)(m0 + (tid >> 5)) * DICT + n0);
#pragma unroll
        for (int s = 0; s < 16; ++s) {
            trow[(tid & 31)] = z;
            trow += (size_t)8 * DICT / 4;   // advance 8 rows
        }
    }

    // ---- candidate detection from registers (no feat value writes) ----
    const int crow0 = m0 + wm * 64;
    const int ccol0 = n0 + wn * 64;
#pragma unroll
    for (int fm = 0; fm < 4; ++fm) {
#pragma unroll
        for (int fn = 0; fn < 4; ++fn) {
            const int col = ccol0 + fn * 16 + (lane & 15);
            const float be = b_enc[col];
#pragma unroll
            for (int r = 0; r < 4; ++r) {
                const int row = crow0 + fm * 16 + (lane >> 4) * 4 + r;
                const float val = fmaxf(acc[fm][fn][r] + be, 0.f);
                if (val >= BLf) {
                    const unsigned u = __float_as_uint(val);
                    if (u < BHb) atomicAdd(&fhist[min((u - BLb) >> fs, (unsigned)(FBINS - 1))], 1u);
                    else atomicAdd(&labv, 1u);
                    const unsigned p = atomicAdd(&lcnt, 1u);
                    if (p < BCAP) {
                        ci[p] = (unsigned)(row * DICT + col);
                        cb[p] = u;
                    }
                }
            }
        }
    }
    __syncthreads();
    if (tid == 0) {
        if (labv) atomicAdd(&scal[16], labv);
        const unsigned n = min(lcnt, BCAP);
        if (lcnt > BCAP) atomicExch(&scal[17], 1u);
        sbase = atomicAdd(&scal[2], n);
    }
    __syncthreads();
    const unsigned n = min(lcnt, BCAP);
    const unsigned gb = sbase;
    for (unsigned k = tid; k < n; k += 256) {
        const unsigned g = gb + k;
        if (g < CAND_CAP) { candI[g] = ci[k]; candB[g] = cb[k]; }
        else atomicExch(&scal[17], 1u);
    }
}

// ======== findfine_a: fine-bin of rank TOTK; zone bounds; validate ========
__global__ __launch_bounds__(1024) void findfine_a(const unsigned* __restrict__ fhist,
                                                   unsigned* __restrict__ scal)
{
    __shared__ unsigned fhl[FBINS];
    __shared__ unsigned tsum[1024];
    __shared__ unsigned suffix[1024];
    __shared__ unsigned sfb;
    const int t = threadIdx.x;
    fhl[t * 2] = fhist[t * 2];
    fhl[t * 2 + 1] = fhist[t * 2 + 1];
    tsum[t] = fhl[t * 2] + fhl[t * 2 + 1];
    if (t == 0) sfb = 0xFFFFFFFFu;
    __syncthreads();
    if (t == 0) {
        unsigned run = 0;
        for (int i = 1023; i >= 0; --i) { suffix[i] = run; run += tsum[i]; }
    }
    __syncthreads();
    const unsigned aboveBH = scal[16];
    unsigned cum = aboveBH + suffix[t];
    {
        const unsigned b1 = (unsigned)(t * 2 + 1);
        unsigned nb = cum + fhl[b1];
        if (cum < TOTK && nb >= TOTK) sfb = b1;
        cum = nb;
        const unsigned b0 = (unsigned)(t * 2);
        nb = cum + fhl[b0];
        if (cum < TOTK && nb >= TOTK) sfb = b0;
    }
    __syncthreads();
    if (t == 0) {
        const unsigned BLb = scal[20], BHb = scal[21];
        bool ok = (sfb != 0xFFFFFFFFu) && (scal[17] == 0u) && (scal[2] <= CAND_CAP);
        if (ok) {
            const int fs = fshift_calc(BLb, BHb);
            const unsigned flo = BLb + (sfb << fs);
            const unsigned fhi = BLb + ((sfb + 1u) << fs) - 1u;
            const float zLo = __uint_as_float(flo) - DELTA;
            const float zHi = __uint_as_float(fhi) + DELTA;
            const unsigned ZL = __float_as_uint(fmaxf(zLo, 1e-30f));
            const unsigned ZH = __float_as_uint(zHi);
            ok = ok && (ZL >= BLb);
            scal[6] = ZL;
            scal[7] = ZH;
        }
        scal[18] = ok ? 1u : 0u;
    }
}

// ======== findfine_b: multi-block above-zone count + zone gather ========
__global__ __launch_bounds__(256) void findfine_b(const unsigned* __restrict__ candB,
                                                  const unsigned* __restrict__ candI,
                                                  unsigned* __restrict__ scal,
                                                  unsigned* __restrict__ c2idx)
{
    if (!scal[18]) return;
    __shared__ unsigned lz[ZLOC_CAP];
    __shared__ unsigned red[256];
    __shared__ unsigned lcnt, sbase;
    const int tid = threadIdx.x;
    if (tid == 0) lcnt = 0;
    __syncthreads();
    const unsigned ZL = scal[6], ZH = scal[7];
    const unsigned C = min(scal[2], CAND_CAP);
    const unsigned stride = gridDim.x * blockDim.x;
    unsigned above = 0;
    for (unsigned i = blockIdx.x * blockDim.x + tid; i < C; i += stride) {
        const unsigned u = candB[i];
        if (u > ZH) above++;
        else if (u >= ZL) {
            const unsigned p = atomicAdd(&lcnt, 1u);
            if (p < ZLOC_CAP) lz[p] = candI[i];
        }
    }
    red[tid] = above;
    __syncthreads();
    for (int s = 128; s; s >>= 1) {
        if (tid < s) red[tid] += red[tid + s];
        __syncthreads();
    }
    if (tid == 0) {
        if (red[0]) atomicAdd(&scal[8], red[0]);
        const unsigned n = min(lcnt, ZLOC_CAP);
        sbase = atomicAdd(&scal[9], n);
    }
    __syncthreads();
    const unsigned n = min(lcnt, ZLOC_CAP);
    const unsigned gb = sbase;
    for (unsigned k = tid; k < n; k += 256) {
        const unsigned g = gb + k;
        if (g < C2_CAP) c2idx[g] = lz[k];
    }
}

// ====== exact OpenBLAS-mimic recompute of zone candidates ======
__global__ __launch_bounds__(256) void refine2_kernel(
    const float* __restrict__ x, const float* __restrict__ W,
    const float* __restrict__ b_enc, const float* __restrict__ b_dec,
    const unsigned* __restrict__ scal, const unsigned* __restrict__ c2idx,
    float* __restrict__ c2val)
{
    const unsigned n = min(scal[9], C2_CAP);
    const size_t stride = (size_t)gridDim.x * blockDim.x;
    for (unsigned c = blockIdx.x * blockDim.x + threadIdx.x; c < n; c += stride) {
        const unsigned i = c2idx[c];
        const int m = (int)(i >> 14);
        const int d = (int)(i & (DICT - 1));
        const float* xr = x + (size_t)m * INDIM;
        const float* wr = W + (size_t)d * INDIM;
        const int kb[4] = {0, 384, 704, 1024};
        float tot = 0.f;
        for (int p = 0; p < 3; ++p) {
            float a = 0.f;
#pragma unroll 8
            for (int k = kb[p]; k < kb[p + 1]; ++k)
                a = fmaf(xr[k] - b_dec[k], wr[k], a);
            tot = (p == 0) ? a : (tot + a);
        }
        c2val[c] = tot + b_enc[d];
    }
}

// ====== zone order-statistic: hist + find vj in ONE kernel ======
__device__ inline int zone_shift(unsigned ZL, unsigned ZH) {
    const unsigned range = ZH - ZL + 1u;
    int shift = 0;
    while ((range >> shift) > (unsigned)ZBINS) ++shift;
    return shift;
}

__global__ __launch_bounds__(1024) void findv_kernel(const float* __restrict__ c2val,
                                                     unsigned* __restrict__ scal)
{
    __shared__ unsigned h[ZBINS];
    __shared__ float mem[1024];
    __shared__ unsigned mcnt;
    __shared__ unsigned sbsel, sjj;
    const int t = threadIdx.x;
    h[t] = 0;
    h[t + 1024] = 0;
    if (t == 0) mcnt = 0;
    __syncthreads();
    const unsigned n = min(scal[9], C2_CAP);
    const unsigned ZL = scal[6], ZH = scal[7];
    const int shift = zone_shift(ZL, ZH);
    for (unsigned i = t; i < n; i += 1024) {
        const unsigned bits = __float_as_uint(c2val[i]);
        const unsigned idx = (bits <= ZL) ? 0u : min((unsigned)(ZBINS - 1), (bits - ZL) >> shift);
        atomicAdd(&h[idx], 1u);
    }
    __syncthreads();
    unsigned j = TOTK - scal[8];
    if (j > n) j = n;
    if (t == 0) {
        unsigned cum = 0, bsel = 0, jj = j;
        for (int i = ZBINS - 1; i >= 0; --i) {
            const unsigned nb = cum + h[i];
            if (cum < j && nb >= j) { bsel = (unsigned)i; jj = j - cum; }
            cum = nb;
        }
        sbsel = bsel; sjj = jj;
    }
    __syncthreads();
    const unsigned bsel = sbsel, jj = sjj;
    for (unsigned i = t; i < n; i += 1024) {
        const unsigned bits = __float_as_uint(c2val[i]);
        const unsigned idx = (bits <= ZL) ? 0u : min((unsigned)(ZBINS - 1), (bits - ZL) >> shift);
        if (idx == bsel) {
            const unsigned p = atomicAdd(&mcnt, 1u);
            if (p < 1024) mem[p] = c2val[i];
        }
    }
    __syncthreads();
    const unsigned m = min(mcnt, 1024u);
    for (unsigned i = t; i < m; i += 1024) {
        const float v = mem[i];
        unsigned g = 0, eq = 0;
        for (unsigned d = 0; d < m; ++d) {
            g += (mem[d] > v) ? 1u : 0u;
            eq += (mem[d] == v) ? 1u : 0u;
        }
        if (g < jj && g + eq >= jj) scal[11] = __float_as_uint(v);
    }
}

// ============ transpose W_dec -> Wt(bf16) [DICT][INDIM] ============
__global__ void transpose_kernel(const float* __restrict__ W, ushort* __restrict__ Wt)
{
    __shared__ float t[32][33];
    const int x0 = blockIdx.x * 32;
    const int y0 = blockIdx.y * 32;
    const int tx = threadIdx.x, ty = threadIdx.y;
    for (int r = ty; r < 32; r += 8)
        t[r][tx] = W[(size_t)(y0 + r) * DICT + x0 + tx];
    __syncthreads();
    for (int r = ty; r < 32; r += 8)
        Wt[(size_t)(x0 + r) * INDIM + y0 + tx] = bf16_rne_u(t[tx][r]);
}

// ====== scatter kept (above-zone approx + in-zone exact) ======
__global__ __launch_bounds__(256) void scatter_all(
    unsigned* __restrict__ scal, const unsigned* __restrict__ candI,
    const unsigned* __restrict__ candB, const unsigned* __restrict__ c2idx,
    const float* __restrict__ c2val,
    float* __restrict__ feat, uint2* __restrict__ entries,
    unsigned* __restrict__ rowcnt)
{
    if (!scal[18]) return;
    __shared__ unsigned red[256];
    const unsigned stride = gridDim.x * blockDim.x;
    unsigned kept = 0;
    // above-zone candidates (approx stored value)
    {
        const unsigned C = min(scal[2], CAND_CAP);
        const unsigned ZH = scal[7];
        for (unsigned i = blockIdx.x * blockDim.x + threadIdx.x; i < C; i += stride) {
            const unsigned u = candB[i];
            if (u > ZH) {
                const unsigned idx = candI[i];
                feat[idx] = __uint_as_float(u);
                const unsigned row = idx >> 14;
                const unsigned p = atomicAdd(&rowcnt[row], 1u);
                if (p < ROW_CAP)
                    entries[(size_t)row * ROW_CAP + p] = make_uint2(idx & (DICT - 1), u);
                kept++;
            }
        }
    }
    // in-zone kept (exact values, v >= vj)
    {
        const unsigned n = min(scal[9], C2_CAP);
        const float vj = __uint_as_float(scal[11]);
        for (unsigned i = blockIdx.x * blockDim.x + threadIdx.x; i < n; i += stride) {
            const float v = c2val[i];
            if (v >= vj) {
                const unsigned idx = c2idx[i];
                feat[idx] = v;
                const unsigned row = idx >> 14;
                const unsigned p = atomicAdd(&rowcnt[row], 1u);
                if (p < ROW_CAP)
                    entries[(size_t)row * ROW_CAP + p] =
                        make_uint2(idx & (DICT - 1), __float_as_uint(v));
                kept++;
            }
        }
    }
    red[threadIdx.x] = kept;
    __syncthreads();
    for (int s = 128; s; s >>= 1) {
        if (threadIdx.x < s) red[threadIdx.x] += red[threadIdx.x + s];
        __syncthreads();
    }
    if (threadIdx.x == 0 && red[0]) atomicAdd(&scal[4], red[0]);
}

// ====== decode from per-row lists (bf16 Wt, no feat read) ======
__global__ __launch_bounds__(256) void decode2_kernel(
    const unsigned* __restrict__ scal, const uint2* __restrict__ entries,
    const unsigned* __restrict__ rowcnt, const ushort* __restrict__ Wt,
    const float* __restrict__ b_dec, const float* __restrict__ x,
    float* __restrict__ recon, double* __restrict__ loss_sum)
{
    if (!scal[18]) return;
    __shared__ uint2 lst[ROW_CAP];
    __shared__ double redd[256];
    const int row = blockIdx.x;
    const int tid = threadIdx.x;
    const unsigned n = min(rowcnt[row], (unsigned)ROW_CAP);
    for (unsigned i = tid; i < n; i += 256) lst[i] = entries[(size_t)row * ROW_CAP + i];
    __syncthreads();
    float4 acc = make_float4(0.f, 0.f, 0.f, 0.f);
    for (unsigned e = 0; e < n; ++e) {
        const uint2 en = lst[e];
        const float v = __uint_as_float(en.y);
        const ushort4 w4 = *reinterpret_cast<const ushort4*>(Wt + (size_t)en.x * INDIM + tid * 4);
        acc.x = fmaf(v, bf16_to_f(w4.x), acc.x);
        acc.y = fmaf(v, bf16_to_f(w4.y), acc.y);
        acc.z = fmaf(v, bf16_to_f(w4.z), acc.z);
        acc.w = fmaf(v, bf16_to_f(w4.w), acc.w);
    }
    const float4 bd = reinterpret_cast<const float4*>(b_dec)[tid];
    acc.x += bd.x; acc.y += bd.y; acc.z += bd.z; acc.w += bd.w;
    reinterpret_cast<float4*>(recon + (size_t)row * INDIM)[tid] = acc;
    const float4 xv = reinterpret_cast<const float4*>(x + (size_t)row * INDIM)[tid];
    const double d0 = (double)acc.x - (double)xv.x;
    const double d1 = (double)acc.y - (double)xv.y;
    const double d2 = (double)acc.z - (double)xv.z;
    const double d3 = (double)acc.w - (double)xv.w;
    redd[tid] = d0 * d0 + d1 * d1 + d2 * d2 + d3 * d3;
    __syncthreads();
    for (int s = 128; s; s >>= 1) {
        if (tid < s) redd[tid] += redd[tid + s];
        __syncthreads();
    }
    if (tid == 0) atomicAdd(loss_sum, redd[0]);
}

__global__ void finalize_kernel(const unsigned* __restrict__ scal, float* __restrict__ tail)
{
    const double* loss_d = reinterpret_cast<const double*>(&scal[12]);
    const float rec = (float)(loss_d[0] / (double)((size_t)BATCH * INDIM));
    tail[0] = rec;
    tail[1] = rec;
    tail[2] = 0.f;
    tail[3] = (float)scal[4] / (float)BATCH;
}

extern "C" void kernel_launch(void* const* d_in, const int* in_sizes, int n_in,
                              void* d_out, int out_size, void* d_ws, size_t ws_size,
                              hipStream_t stream)
{
    const float* x     = (const float*)d_in[0];
    const float* W_enc = (const float*)d_in[1];
    const float* b_enc = (const float*)d_in[2];
    const float* W_dec = (const float*)d_in[3];
    const float* b_dec = (const float*)d_in[4];

    float* recon = (float*)d_out;
    float* feat  = recon + (size_t)BATCH * INDIM;
    float* tail  = feat + NFEAT;

    unsigned* pshist = (unsigned*)((char*)d_ws + PSH_OFF);
    unsigned* fhist  = (unsigned*)((char*)d_ws + FH_OFF);
    unsigned* scal   = (unsigned*)((char*)d_ws + SCAL_OFF);
    unsigned* rowcnt = (unsigned*)((char*)d_ws + ROWC_OFF);
    unsigned* candI  = (unsigned*)((char*)d_ws + CANDI_OFF);
    unsigned* candB  = (unsigned*)((char*)d_ws + CANDB_OFF);
    unsigned* c2idx  = (unsigned*)((char*)d_ws + C2I_OFF);
    float*    c2val  = (float*)   ((char*)d_ws + C2V_OFF);
    uint2*    entries= (uint2*)   ((char*)d_ws + ENT_OFF);
    ushort*   Ahi    = (ushort*)  ((char*)d_ws + AHI_OFF);
    ushort*   Bhi    = (ushort*)  ((char*)d_ws + BHI_OFF);
    ushort*   Wt     = (ushort*)  ((char*)d_ws + WT_OFF);
    double*   loss_sum = (double*)&scal[12];

    hipMemsetAsync(d_ws, 0, MEMSET0, stream);   // pshist/fhist/scal/rowcnt

    split_kernel<<<2048, 256, 0, stream>>>(x, W_enc, b_dec, Ahi, Bhi);
    presample_mfma<<<128, 256, 0, stream>>>(Ahi, Bhi, b_enc, pshist);
    presample_find<<<1, 1024, 0, stream>>>(pshist, scal);
    encode_main<<<dim3(128, 32), 256, 0, stream>>>(Ahi, Bhi, b_enc, scal, fhist, candI, candB, feat);
    findfine_a<<<1, 1024, 0, stream>>>(fhist, scal);
    findfine_b<<<256, 256, 0, stream>>>(candB, candI, scal, c2idx);

    refine2_kernel<<<128, 256, 0, stream>>>(x, W_enc, b_enc, b_dec, scal, c2idx, c2val);
    findv_kernel<<<1, 1024, 0, stream>>>(c2val, scal);

    transpose_kernel<<<dim3(DICT / 32, INDIM / 32), dim3(32, 8), 0, stream>>>(W_dec, Wt);

    scatter_all<<<256, 256, 0, stream>>>(scal, candI, candB, c2idx, c2val, feat, entries, rowcnt);
    decode2_kernel<<<BATCH, 256, 0, stream>>>(scal, entries, rowcnt, Wt, b_dec, x, recon, loss_sum);

    finalize_kernel<<<1, 1, 0, stream>>>(scal, tail);
}